// Round 10
// baseline (115.540 us; speedup 1.0000x reference)
//
#include <hip/hip_runtime.h>

#define PI_F 3.14159265358979323846f

typedef _Float16 half2v __attribute__((ext_vector_type(2)));
typedef _Float16 half4v __attribute__((ext_vector_type(4)));
typedef _Float16 half8v __attribute__((ext_vector_type(8)));
typedef float f32x4 __attribute__((ext_vector_type(4)));

struct C2 { float x, y; };
__device__ __forceinline__ C2 cmul(C2 a, C2 b) {
    return C2{a.x * b.x - a.y * b.y, a.x * b.y + a.y * b.x};
}

__device__ __forceinline__ void gate1(float& re, float& im, int l, int w,
                                      C2 m00, C2 m01, C2 m10, C2 m11) {
    int mask = 1 << (3 - w);
    float pre = __shfl_xor(re, mask, 64);
    float pim = __shfl_xor(im, mask, 64);
    bool b = (l & mask) != 0;
    C2 d = b ? m11 : m00;
    C2 o = b ? m10 : m01;
    float nre = d.x * re - d.y * im + o.x * pre - o.y * pim;
    float nim = d.x * im + d.y * re + o.x * pim + o.y * pre;
    re = nre; im = nim;
}

// r9 (launch_bounds(256,2), spill-free, VGPR 80) + r8's pairwise phase-2.
// r8's interleave failed ONLY because the old 64-VGPR cap spilled its 16-acc
// working set (WRITE 117MB); with the 256-budget it fits (~110 VGPR). 4
// independent MFMA chains per ks-step halve phase-2's latency-bound span.
__global__ __launch_bounds__(256, 2) void qnn_one(
    const float* __restrict__ xg,
    const float* __restrict__ w1g, const float* __restrict__ b1g,
    const float* __restrict__ w2g, const float* __restrict__ b2g,
    const float* __restrict__ dwg, const float* __restrict__ dbg,
    const float* __restrict__ qpg,
    const float* __restrict__ pwg, const float* __restrict__ pbg,
    float* __restrict__ out, int Btot)
{
    const int b4 = blockIdx.x << 2;
    const int t = threadIdx.x;
    const int lane = t & 63;
    const int wv = __builtin_amdgcn_readfirstlane(t >> 6);
    const int kq = lane >> 4;        // operand k-quad == C/D row-quad
    const int lm = lane & 15;

    // xhl: padded 30x40 input as half2{hi,lo}; stride 40 words == 8 mod 32.
    __shared__ __align__(16) unsigned xhl[1200];
    // w2f: conv2 B-fragments, float4 = half8 per (ks,nt,lane). Persistent.
    __shared__ __align__(16) float4 w2f[640];
    // ovl: prologue = padded w2 stage (32 oc x 145 floats = 18560B);
    //      main = p1f (f16 [16r][20c][24ch] = 15360B) + p2s (f32 6272B).
    __shared__ __align__(16) char ovl[21632];
    __shared__ __align__(16) float angp[64];   // [element 0..3][16 partials]
    __shared__ float grot[64];                 // rot gate matrices
    __shared__ float gent[24];                 // entangler phases

    float*     w2s = (float*)ovl;              // prologue only
    _Float16*  p1f = (_Float16*)ovl;           // main loop
    float*     p2s = (float*)(ovl + 15360);    // main loop

    // ---- x-staging addresses (thread-invariant across elements)
    int xoff[5];
    {
        int y = t / 40, x = t - y * 40;
        #pragma unroll
        for (int it = 0; it < 5; ++it) {
            bool ok = (t + it * 256 < 1200) && y >= 1 && y <= 28 && x >= 1 && x <= 28;
            xoff[it] = ok ? (y * 28 + x - 29) : -1;
            x += 16; y += 6; if (x >= 40) { x -= 40; y += 1; }
        }
    }

    // ---- prefetch x(element 0): longest-latency chain, issue first
    float xr[5];
    {
        const float* xb = xg + (size_t)b4 * 784;
        #pragma unroll
        for (int it = 0; it < 5; ++it)
            xr[it] = (xoff[it] >= 0 && b4 < Btot) ? xb[xoff[it]] : 0.f;
    }

    // ---- stage w2 into PADDED LDS layout (coalesced loads, direct stores)
    #pragma unroll
    for (int i = 0; i < 18; ++i) {
        int m = t + i * 256;
        int oc = m / 144;
        int k = m - oc * 144;
        w2s[oc * 145 + k] = w2g[m];
    }

    // ---- dense weights -> registers (coalesced; one-time prologue cost)
    float dwr0[7], dwr1[7], dwr2[7], dwr3[7];
    #pragma unroll
    for (int k2 = 0; k2 < 7; ++k2) {
        int i = t + k2 * 256;
        bool ok = i < 1568;
        dwr0[k2] = ok ? dwg[i] : 0.f;
        dwr1[k2] = ok ? dwg[1568 + i] : 0.f;
        dwr2[k2] = ok ? dwg[3136 + i] : 0.f;
        dwr3[k2] = ok ? dwg[4704 + i] : 0.f;
    }

    // ---- conv1 B-fragment (w1 = 144 floats, trivial)
    half4v bC1 = {(_Float16)0.f, (_Float16)0.f, (_Float16)0.f, (_Float16)0.f};
    if (kq < 3) {
        #pragma unroll
        for (int j = 0; j < 3; ++j)
            bC1[j] = (_Float16)w1g[lm * 9 + kq * 3 + j];
    }
    float bias1 = b1g[lm];
    float b20 = b2g[lm], b21 = b2g[16 + lm];

    // ---- quantum gate matrices into LDS (tiny, read in phase 3 only)
    if (t < 8) {                     // M = RZ(a2) RY(a1) RX(a0)
        int layer = t >> 2, q = t & 3;
        int st = layer * 18;
        float a0 = qpg[st + 3 * q], a1 = qpg[st + 3 * q + 1], a2 = qpg[st + 3 * q + 2];
        float cx = cosf(0.5f * a0), sx = sinf(0.5f * a0);
        float cy = cosf(0.5f * a1), sy = sinf(0.5f * a1);
        float cz = cosf(0.5f * a2), sz = sinf(0.5f * a2);
        C2 T00{cy * cx,  sy * sx}, T01{-sy * cx, -cy * sx};
        C2 T10{sy * cx, -cy * sx}, T11{ cy * cx, -sy * sx};
        C2 E0{cz, -sz}, E1{cz, sz};
        C2 m00 = cmul(E0, T00), m01 = cmul(E0, T01);
        C2 m10 = cmul(E1, T10), m11 = cmul(E1, T11);
        float* gm = grot + t * 8;
        gm[0] = m00.x; gm[1] = m00.y; gm[2] = m01.x; gm[3] = m01.y;
        gm[4] = m10.x; gm[5] = m10.y; gm[6] = m11.x; gm[7] = m11.y;
    }
    if (t >= 32 && t < 44) {         // entangler RZ phases
        int k = t - 32;
        float e = qpg[(k / 6) * 18 + 12 + (k % 6)];
        gent[k * 2]     = cosf(0.5f * e);
        gent[k * 2 + 1] = sinf(0.5f * e);
    }

    // ---- store xhl(0) (own region, independent of overlay)
    #pragma unroll
    for (int it = 0; it < 5; ++it) {
        int j = t + it * 256;
        if (it < 4 || j < 1200) {
            float v = xr[it];
            _Float16 h = (_Float16)v;
            _Float16 lo = (_Float16)(v - (float)h);
            half2v p; p.x = h; p.y = lo;
            xhl[j] = __builtin_bit_cast(unsigned, p);
        }
    }

    __syncthreads();   // P1: w2s staged

    // ---- build conv2 B-fragments (gather from PADDED w2s: row stride 145,
    // 145 mod 32 = 17 (odd) -> 16 oc values land on 16 distinct banks)
    for (int ee = t; ee < 640; ee += 256) {
        int kstep = ee >> 7, rem = ee & 127;
        int ntile = rem >> 6, ln = rem & 63;
        int fkq = ln >> 4, n = ln & 15;
        int oc = ntile * 16 + n;
        int pi = kstep * 2 + (fkq >> 1);
        bool ok = pi < 9;
        const float* wp = w2s + oc * 145 + (fkq & 1) * 72 + (ok ? pi : 0);
        half8v h;
        #pragma unroll
        for (int jj = 0; jj < 8; ++jj)
            h[jj] = ok ? (_Float16)wp[jj * 9] : (_Float16)0.f;
        w2f[ee] = __builtin_bit_cast(float4, h);
    }

    __syncthreads();   // P2: w2f built, w2s dead

    {   // zero p1f (borders persist; interior rewritten per element)
        uint4 z4 = {0u, 0u, 0u, 0u};
        uint4* p4 = (uint4*)p1f;
        #pragma unroll
        for (int j = 0; j < 4; ++j) {
            int i = t + j * 256;
            if (i < 960) p4[i] = z4;
        }
    }
    {   // prefetch x(1)
        const float* xb = xg + (size_t)(b4 + 1) * 784;
        #pragma unroll
        for (int it = 0; it < 5; ++it)
            xr[it] = (xoff[it] >= 0 && b4 + 1 < Btot) ? xb[xoff[it]] : 0.f;
    }

    // ---- element-invariant geometry --------------------------------------
    const int kyc = (kq < 3) ? kq : 0;
    int base_i, wa_i, X_i, c_i;
    {
        int pos1 = lm & 3, pyo = pos1 >> 1, pxo = pos1 & 1;
        int p14 = wv * 4 + (lm >> 2);
        int Y = p14 / 14, X = p14 - Y * 14;
        base_i = (2 * Y + pyo + kyc) * 40 + 2 * X + pxo;
        X_i = X;
        int q14 = wv * 4 + kq;
        int r = q14 / 14, c = q14 - r * 14;
        wa_i = ((r + 1) * 20 + (c + 1)) * 24 + lm;
        c_i = c;
    }
    const int ich = (kq & 1) * 8;
    int a2_[4], quadO_[4];
    #pragma unroll
    for (int it2 = 0; it2 < 4; ++it2) {
        int tile = wv + it2 * 4;
        int tt = (tile < 13) ? tile : 12;      // clamp -> always-valid address
        int m = tt * 16 + lm;
        int quad = m >> 2; if (quad > 48) quad = 48;
        int pos = m & 3;
        int Y = quad / 7, X = quad - Y * 7;
        int py = 2 * Y + (pos >> 1), px = 2 * X + (pos & 1);
        a2_[it2] = (py * 20 + px) * 24 + ich;
        quadO_[it2] = tile * 4 + kq;           // >= 49 for clamped tiles
    }
    int koff_[5];
    #pragma unroll
    for (int ks = 0; ks < 5; ++ks) {
        int pi = ks * 2 + (kq >> 1); if (pi > 8) pi = 8;   // pad k -> zero B
        int ky = (pi >= 6) ? 2 : ((pi >= 3) ? 1 : 0);
        int kx = pi - ky * 3;
        koff_[ks] = (ky * 20 + kx) * 24;
    }

    __syncthreads();   // P3: p1f zeroed, xhl(0) visible

    for (int e = 0; e < 4; ++e) {
        // ---------------- phase 1: conv1 via MFMA 16x16x16 (hi+lo) ----------
        {
            int base = base_i, wa = wa_i, X = X_i, c = c_i;
            for (int tile = wv; tile < 49; tile += 4) {
                unsigned u0 = xhl[base], u1 = xhl[base + 1], u2 = xhl[base + 2];
                half2v h0 = __builtin_bit_cast(half2v, u0);
                half2v h1 = __builtin_bit_cast(half2v, u1);
                half2v h2 = __builtin_bit_cast(half2v, u2);
                half4v ah = {h0.x, h1.x, h2.x, (_Float16)0.f};
                half4v al = {h0.y, h1.y, h2.y, (_Float16)0.f};
                f32x4 acc = {bias1, bias1, bias1, bias1};
                acc = __builtin_amdgcn_mfma_f32_16x16x16f16(ah, bC1, acc, 0, 0, 0);
                acc = __builtin_amdgcn_mfma_f32_16x16x16f16(al, bC1, acc, 0, 0, 0);
                float v = fmaxf(fmaxf(fmaxf(acc.x, acc.y), fmaxf(acc.z, acc.w)), 0.f);
                p1f[wa] = (_Float16)v;
                // p-index += 16 on a 14-wide grid: add-and-select deltas
                X += 2; bool wR = X >= 14; base += wR ? 136 : 84; if (wR) X -= 14;
                c += 2; bool wW = c >= 14; wa   += wW ? 672 : 528; if (wW) c -= 14;
            }
        }
        __syncthreads();   // B1: xhl(e) dead, p1f(e) ready

        // ---- store xhl(e+1) from prefetch regs; issue prefetch x(e+2)
        if (e < 3) {
            #pragma unroll
            for (int it = 0; it < 5; ++it) {
                int j = t + it * 256;
                if (it < 4 || j < 1200) {
                    float v = xr[it];
                    _Float16 h = (_Float16)v;
                    _Float16 lo = (_Float16)(v - (float)h);
                    half2v p; p.x = h; p.y = lo;
                    xhl[j] = __builtin_bit_cast(unsigned, p);
                }
            }
            if (e < 2) {
                const float* xb = xg + (size_t)(b4 + e + 2) * 784;
                #pragma unroll
                for (int it = 0; it < 5; ++it)
                    xr[it] = (xoff[it] >= 0 && b4 + e + 2 < Btot) ? xb[xoff[it]] : 0.f;
            }
        }

        // ---------------- phase 2: conv2 MFMA 16x16x32, pool+relu -> p2s ----
        // Pairwise interleave: 4 independent MFMA chains per ks-step (16 acc
        // VGPRs - fits the 256-budget spill-free). B-frags from LDS in-loop.
        // Branch-free nest: clamped addresses, qO<49 store guard.
        {
            const float4* wf = w2f;
            #pragma unroll
            for (int pr = 0; pr < 2; ++pr) {
                const int iA = pr * 2, iB = pr * 2 + 1;
                f32x4 accA0 = {b20, b20, b20, b20};
                f32x4 accA1 = {b21, b21, b21, b21};
                f32x4 accB0 = {b20, b20, b20, b20};
                f32x4 accB1 = {b21, b21, b21, b21};
                __builtin_amdgcn_s_setprio(1);
                #pragma unroll
                for (int ks = 0; ks < 5; ++ks) {
                    half8v aA = *(const half8v*)(&p1f[a2_[iA] + koff_[ks]]);
                    half8v aB = *(const half8v*)(&p1f[a2_[iB] + koff_[ks]]);
                    half8v B0 = __builtin_bit_cast(half8v, wf[(ks * 2 + 0) * 64 + lane]);
                    half8v B1 = __builtin_bit_cast(half8v, wf[(ks * 2 + 1) * 64 + lane]);
                    accA0 = __builtin_amdgcn_mfma_f32_16x16x32_f16(aA, B0, accA0, 0, 0, 0);
                    accB0 = __builtin_amdgcn_mfma_f32_16x16x32_f16(aB, B0, accB0, 0, 0, 0);
                    accA1 = __builtin_amdgcn_mfma_f32_16x16x32_f16(aA, B1, accA1, 0, 0, 0);
                    accB1 = __builtin_amdgcn_mfma_f32_16x16x32_f16(aB, B1, accB1, 0, 0, 0);
                }
                __builtin_amdgcn_s_setprio(0);
                int qA = quadO_[iA], qB = quadO_[iB];
                if (qA < 49) {
                    float v0 = fmaxf(fmaxf(fmaxf(accA0.x, accA0.y), fmaxf(accA0.z, accA0.w)), 0.f);
                    float v1 = fmaxf(fmaxf(fmaxf(accA1.x, accA1.y), fmaxf(accA1.z, accA1.w)), 0.f);
                    p2s[lm * 49 + qA] = v0;         // oc = lm
                    p2s[784 + lm * 49 + qA] = v1;   // oc = 16 + lm
                }
                if (qB < 49) {
                    float v0 = fmaxf(fmaxf(fmaxf(accB0.x, accB0.y), fmaxf(accB0.z, accB0.w)), 0.f);
                    float v1 = fmaxf(fmaxf(fmaxf(accB1.x, accB1.y), fmaxf(accB1.z, accB1.w)), 0.f);
                    p2s[lm * 49 + qB] = v0;
                    p2s[784 + lm * 49 + qB] = v1;
                }
            }
        }
        __syncthreads();   // B2: p2s(e) complete

        // ---------------- dense: p2s x register dw -> angp[e] ---------------
        {
            float dp0 = 0.f, dp1 = 0.f, dp2 = 0.f, dp3 = 0.f;
            #pragma unroll
            for (int k2 = 0; k2 < 7; ++k2) {
                int i = t + k2 * 256;
                if (k2 < 6 || i < 1568) {
                    float v = p2s[i];
                    dp0 = fmaf(v, dwr0[k2], dp0);
                    dp1 = fmaf(v, dwr1[k2], dp1);
                    dp2 = fmaf(v, dwr2[k2], dp2);
                    dp3 = fmaf(v, dwr3[k2], dp3);
                }
            }
            #pragma unroll
            for (int m = 32; m >= 1; m >>= 1) {
                dp0 += __shfl_xor(dp0, m, 64);
                dp1 += __shfl_xor(dp1, m, 64);
                dp2 += __shfl_xor(dp2, m, 64);
                dp3 += __shfl_xor(dp3, m, 64);
            }
            if (lane == 0) {
                float4 dpv = {dp0, dp1, dp2, dp3};
                *(float4*)&angp[e * 16 + wv * 4] = dpv;
            }
        }
        // phase1(e+1) writes p1f (disjoint from p2s); xhl(e+1) pre-B2. Safe.
    }
    __syncthreads();   // angp fully visible

    // ---------------- phase 3: quantum sim + post linear, 1 element/wave ----
    {
        const int bi = b4 + wv;
        const float* ap = angp + wv * 16;
        float4 a0v = *(const float4*)(ap);
        float4 a1v = *(const float4*)(ap + 4);
        float4 a2v = *(const float4*)(ap + 8);
        float4 a3v = *(const float4*)(ap + 12);
        float aw[4] = {a0v.x + a1v.x + a2v.x + a3v.x + dbg[0],
                       a0v.y + a1v.y + a2v.y + a3v.y + dbg[1],
                       a0v.z + a1v.z + a2v.z + a3v.z + dbg[2],
                       a0v.w + a1v.w + a2v.w + a3v.w + dbg[3]};
        int l = lm;
        float re = (l == 0) ? 1.f : 0.f;
        float im = 0.f;
        #pragma unroll
        for (int w = 0; w < 4; ++w) {        // initial RY(angle * pi)
            float th = aw[w] * (PI_F * 0.5f);
            float cth = __cosf(th), sth = __sinf(th);
            gate1(re, im, l, w, C2{cth, 0.f}, C2{-sth, 0.f}, C2{sth, 0.f}, C2{cth, 0.f});
        }
        #pragma unroll
        for (int layer = 0; layer < 2; ++layer) {
            #pragma unroll
            for (int q = 0; q < 4; ++q) {    // precomputed rot gates (uniform)
                const float* gm = grot + (layer * 4 + q) * 8;
                gate1(re, im, l, q, C2{gm[0], gm[1]}, C2{gm[2], gm[3]},
                                     C2{gm[4], gm[5]}, C2{gm[6], gm[7]});
            }
            const int pi_[6] = {0, 0, 0, 1, 1, 2};
            const int pj_[6] = {1, 2, 3, 2, 3, 3};
            #pragma unroll
            for (int k = 0; k < 6; ++k) {    // CNOT(i->j) then RZ on j
                int i = pi_[k], j = pj_[k];
                const float* em = gent + (layer * 6 + k) * 2;
                float ce = em[0], se = em[1];
                int maskj = 1 << (3 - j);
                float pre = __shfl_xor(re, maskj, 64);
                float pim = __shfl_xor(im, maskj, 64);
                bool ci = ((l >> (3 - i)) & 1) != 0;
                re = ci ? pre : re;
                im = ci ? pim : im;
                bool bj = (l & maskj) != 0;
                C2 ph{ce, bj ? se : -se};
                C2 rr = cmul(C2{re, im}, ph);
                re = rr.x; im = rr.y;
            }
        }
        float pr = re * re + im * im;
        float z0 = ((l >> 3) & 1) ? -pr : pr;
        float z1 = ((l >> 2) & 1) ? -pr : pr;
        float z2 = ((l >> 1) & 1) ? -pr : pr;
        float z3 = (l & 1)        ? -pr : pr;
        #pragma unroll
        for (int m = 1; m <= 8; m <<= 1) {
            z0 += __shfl_xor(z0, m, 64);
            z1 += __shfl_xor(z1, m, 64);
            z2 += __shfl_xor(z2, m, 64);
            z3 += __shfl_xor(z3, m, 64);
        }
        if (lane < 10 && bi < Btot) {
            float4 pw4 = *(const float4*)(pwg + lane * 4);
            float o = pbg[lane];
            o = fmaf(z0, pw4.x, o); o = fmaf(z1, pw4.y, o);
            o = fmaf(z2, pw4.z, o); o = fmaf(z3, pw4.w, o);
            out[(size_t)bi * 10 + lane] = o;
        }
    }
}

extern "C" void kernel_launch(void* const* d_in, const int* in_sizes, int n_in,
                              void* d_out, int out_size, void* d_ws, size_t ws_size,
                              hipStream_t stream) {
    const float* x  = (const float*)d_in[0];
    const float* w1 = (const float*)d_in[1];
    const float* b1 = (const float*)d_in[2];
    const float* w2 = (const float*)d_in[3];
    const float* b2 = (const float*)d_in[4];
    const float* dw = (const float*)d_in[5];
    const float* db = (const float*)d_in[6];
    const float* qp = (const float*)d_in[7];
    const float* pw = (const float*)d_in[8];
    const float* pb = (const float*)d_in[9];
    float* out = (float*)d_out;
    int B = in_sizes[0] / 784;   // 4096
    int nb = (B + 3) >> 2;       // 4 elements per block

    qnn_one<<<nb, 256, 0, stream>>>(x, w1, b1, w2, b2, dw, db, qp, pw, pb, out, B);
}

// Round 12
// 108.510 us; speedup vs baseline: 1.0648x; 1.0648x over previous
//
#include <hip/hip_runtime.h>

#define PI_F 3.14159265358979323846f

typedef _Float16 half2v __attribute__((ext_vector_type(2)));
typedef _Float16 half4v __attribute__((ext_vector_type(4)));
typedef _Float16 half8v __attribute__((ext_vector_type(8)));
typedef float f32x4 __attribute__((ext_vector_type(4)));

struct C2 { float x, y; };
__device__ __forceinline__ C2 cmul(C2 a, C2 b) {
    return C2{a.x * b.x - a.y * b.y, a.x * b.y + a.y * b.x};
}

__device__ __forceinline__ void gate1(float& re, float& im, int l, int w,
                                      C2 m00, C2 m01, C2 m10, C2 m11) {
    int mask = 1 << (3 - w);
    float pre = __shfl_xor(re, mask, 64);
    float pim = __shfl_xor(im, mask, 64);
    bool b = (l & mask) != 0;
    C2 d = b ? m11 : m00;
    C2 o = b ? m10 : m01;
    float nre = d.x * re - d.y * im + o.x * pre - o.y * pim;
    float nim = d.x * im + d.y * re + o.x * pim + o.y * pre;
    re = nre; im = nim;
}

// SESSION-BEST configuration (round 3, total 110.2 us), restored verbatim.
// (Round-11 submission of this exact source hit an infra failure - resubmit.)
// Ledger of falsified alternatives (totals): r4 2-elem/block split (137.8),
// r5/r6 regalloc surgery (crash / 1369 scratch-storm), r7 +w2s padding
// (111.2, neutral), r9 launch_bounds(256,2) spill-free (114.3, WORSE despite
// 0 spill - lost latency hiding), r10 pairwise MFMA interleave (115.5).
// Under (256,4) the compiler targets 64 VGPR / 8 waves-SIMD; its ~12 MB
// spill costs ~0.35 TB/s against an idle HBM bus and is cheaper than any
// fat-register variant. Kernel is latency-bound (HBM 2%, MfmaUtil 13%);
// total = fill ~43 (harness poison, HBM-roofline) + kernel ~42.6 + ~24
// dispatch gaps (harness-fixed).
__global__ __launch_bounds__(256, 4) void qnn_one(
    const float* __restrict__ xg,
    const float* __restrict__ w1g, const float* __restrict__ b1g,
    const float* __restrict__ w2g, const float* __restrict__ b2g,
    const float* __restrict__ dwg, const float* __restrict__ dbg,
    const float* __restrict__ qpg,
    const float* __restrict__ pwg, const float* __restrict__ pbg,
    float* __restrict__ out, int Btot)
{
    const int b4 = blockIdx.x << 2;
    const int t = threadIdx.x;
    const int lane = t & 63;
    const int wv = __builtin_amdgcn_readfirstlane(t >> 6);
    const int kq = lane >> 4;        // operand k-quad == C/D row-quad
    const int lm = lane & 15;

    // xhl: padded 30x40 input as half2{hi,lo}; stride 40 words == 8 mod 32
    // banks -> the 4 rows a wave reads tile all 32 banks (conflict-free).
    __shared__ __align__(16) unsigned xhl[1200];
    // w2f: conv2 B-fragments, float4 = half8 per (ks,nt,lane). Persistent.
    __shared__ __align__(16) float4 w2f[640];
    // ovl: prologue = raw w2 stage (4608 floats = 18432B);
    //      main = p1f (f16 [16r][20c][24ch] = 15360B) + p2s (f32 6272B).
    __shared__ __align__(16) char ovl[21632];
    __shared__ __align__(16) float angp[64];   // [element 0..3][16 partials]
    __shared__ float grot[64];                 // rot gate matrices
    __shared__ float gent[24];                 // entangler phases

    float*     w2s = (float*)ovl;              // prologue only
    _Float16*  p1f = (_Float16*)ovl;           // main loop
    float*     p2s = (float*)(ovl + 15360);    // main loop

    // ---- x-staging addresses (thread-invariant across elements)
    int xoff[5];
    {
        int y = t / 40, x = t - y * 40;
        #pragma unroll
        for (int it = 0; it < 5; ++it) {
            bool ok = (t + it * 256 < 1200) && y >= 1 && y <= 28 && x >= 1 && x <= 28;
            xoff[it] = ok ? (y * 28 + x - 29) : -1;
            x += 16; y += 6; if (x >= 40) { x -= 40; y += 1; }
        }
    }

    // ---- prefetch x(element 0): longest-latency load chain, issue first
    float xr[5];
    {
        const float* xb = xg + (size_t)b4 * 784;
        #pragma unroll
        for (int it = 0; it < 5; ++it)
            xr[it] = (xoff[it] >= 0 && b4 < Btot) ? xb[xoff[it]] : 0.f;
    }

    // ---- stage w2 raw into LDS (fully coalesced: 18 float loads/thread)
    #pragma unroll
    for (int i = 0; i < 18; ++i)
        w2s[t + i * 256] = w2g[t + i * 256];

    // ---- dense weights -> registers (coalesced; if regalloc demotes them the
    // fallback reload is also coalesced L2 - benign)
    float dwr0[7], dwr1[7], dwr2[7], dwr3[7];
    #pragma unroll
    for (int k2 = 0; k2 < 7; ++k2) {
        int i = t + k2 * 256;
        bool ok = i < 1568;
        dwr0[k2] = ok ? dwg[i] : 0.f;
        dwr1[k2] = ok ? dwg[1568 + i] : 0.f;
        dwr2[k2] = ok ? dwg[3136 + i] : 0.f;
        dwr3[k2] = ok ? dwg[4704 + i] : 0.f;
    }

    // ---- conv1 B-fragment (w1 = 144 floats, trivial)
    half4v bC1 = {(_Float16)0.f, (_Float16)0.f, (_Float16)0.f, (_Float16)0.f};
    if (kq < 3) {
        #pragma unroll
        for (int j = 0; j < 3; ++j)
            bC1[j] = (_Float16)w1g[lm * 9 + kq * 3 + j];
    }
    float bias1 = b1g[lm];
    float b20 = b2g[lm], b21 = b2g[16 + lm];

    // ---- quantum gate matrices into LDS (tiny, read in phase 3 only)
    if (t < 8) {                     // M = RZ(a2) RY(a1) RX(a0)
        int layer = t >> 2, q = t & 3;
        int st = layer * 18;
        float a0 = qpg[st + 3 * q], a1 = qpg[st + 3 * q + 1], a2 = qpg[st + 3 * q + 2];
        float cx = cosf(0.5f * a0), sx = sinf(0.5f * a0);
        float cy = cosf(0.5f * a1), sy = sinf(0.5f * a1);
        float cz = cosf(0.5f * a2), sz = sinf(0.5f * a2);
        C2 T00{cy * cx,  sy * sx}, T01{-sy * cx, -cy * sx};
        C2 T10{sy * cx, -cy * sx}, T11{ cy * cx, -sy * sx};
        C2 E0{cz, -sz}, E1{cz, sz};
        C2 m00 = cmul(E0, T00), m01 = cmul(E0, T01);
        C2 m10 = cmul(E1, T10), m11 = cmul(E1, T11);
        float* gm = grot + t * 8;
        gm[0] = m00.x; gm[1] = m00.y; gm[2] = m01.x; gm[3] = m01.y;
        gm[4] = m10.x; gm[5] = m10.y; gm[6] = m11.x; gm[7] = m11.y;
    }
    if (t >= 32 && t < 44) {         // entangler RZ phases
        int k = t - 32;
        float e = qpg[(k / 6) * 18 + 12 + (k % 6)];
        gent[k * 2]     = cosf(0.5f * e);
        gent[k * 2 + 1] = sinf(0.5f * e);
    }

    // ---- store xhl(0) (own region, independent of overlay)
    #pragma unroll
    for (int it = 0; it < 5; ++it) {
        int j = t + it * 256;
        if (it < 4 || j < 1200) {
            float v = xr[it];
            _Float16 h = (_Float16)v;
            _Float16 lo = (_Float16)(v - (float)h);
            half2v p; p.x = h; p.y = lo;
            xhl[j] = __builtin_bit_cast(unsigned, p);
        }
    }

    __syncthreads();   // P1: w2s staged

    // ---- build conv2 B-fragments in LDS (one-time transpose, LDS->LDS)
    for (int e = t; e < 640; e += 256) {
        int kstep = e >> 7, rem = e & 127;
        int ntile = rem >> 6, ln = rem & 63;
        int fkq = ln >> 4, n = ln & 15;
        int oc = ntile * 16 + n;
        int pi = kstep * 2 + (fkq >> 1);
        half8v h;
        #pragma unroll
        for (int jj = 0; jj < 8; ++jj) {
            int ic = (fkq & 1) * 8 + jj;
            float v = (pi < 9) ? w2s[oc * 144 + ic * 9 + pi] : 0.f;
            h[jj] = (_Float16)v;
        }
        w2f[e] = __builtin_bit_cast(float4, h);
    }

    __syncthreads();   // P2: w2f built, w2s dead

    {   // zero p1f (borders persist; interior rewritten per element)
        uint4 z4 = {0u, 0u, 0u, 0u};
        uint4* p4 = (uint4*)p1f;
        #pragma unroll
        for (int j = 0; j < 4; ++j) {
            int i = t + j * 256;
            if (i < 960) p4[i] = z4;
        }
    }
    {   // prefetch x(1)
        const float* xb = xg + (size_t)(b4 + 1) * 784;
        #pragma unroll
        for (int it = 0; it < 5; ++it)
            xr[it] = (xoff[it] >= 0 && b4 + 1 < Btot) ? xb[xoff[it]] : 0.f;
    }

    // ---- element-invariant geometry --------------------------------------
    const int kyc = (kq < 3) ? kq : 0;
    int base_i, wa_i, X_i, c_i;
    {
        int pos1 = lm & 3, pyo = pos1 >> 1, pxo = pos1 & 1;
        int p14 = wv * 4 + (lm >> 2);
        int Y = p14 / 14, X = p14 - Y * 14;
        base_i = (2 * Y + pyo + kyc) * 40 + 2 * X + pxo;
        X_i = X;
        int q14 = wv * 4 + kq;
        int r = q14 / 14, c = q14 - r * 14;
        wa_i = ((r + 1) * 20 + (c + 1)) * 24 + lm;
        c_i = c;
    }
    const int ich = (kq & 1) * 8;
    int a2_[4], quadO_[4];
    #pragma unroll
    for (int it2 = 0; it2 < 4; ++it2) {
        int tile = wv + it2 * 4;
        int tt = (tile < 13) ? tile : 12;
        int m = tt * 16 + lm;
        int quad = m >> 2; if (quad > 48) quad = 48;
        int pos = m & 3;
        int Y = quad / 7, X = quad - Y * 7;
        int py = 2 * Y + (pos >> 1), px = 2 * X + (pos & 1);
        a2_[it2] = (py * 20 + px) * 24 + ich;
        quadO_[it2] = tile * 4 + kq;
    }
    int koff_[5];
    #pragma unroll
    for (int ks = 0; ks < 5; ++ks) {
        int pi = ks * 2 + (kq >> 1); if (pi > 8) pi = 8;   // pad k -> zero B
        int ky = (pi >= 6) ? 2 : ((pi >= 3) ? 1 : 0);
        int kx = pi - ky * 3;
        koff_[ks] = (ky * 20 + kx) * 24;
    }

    __syncthreads();   // P3: p1f zeroed, xhl(0) visible

    for (int e = 0; e < 4; ++e) {
        // ---------------- phase 1: conv1 via MFMA 16x16x16 (hi+lo) ----------
        {
            int base = base_i, wa = wa_i, X = X_i, c = c_i;
            for (int tile = wv; tile < 49; tile += 4) {
                unsigned u0 = xhl[base], u1 = xhl[base + 1], u2 = xhl[base + 2];
                half2v h0 = __builtin_bit_cast(half2v, u0);
                half2v h1 = __builtin_bit_cast(half2v, u1);
                half2v h2 = __builtin_bit_cast(half2v, u2);
                half4v ah = {h0.x, h1.x, h2.x, (_Float16)0.f};
                half4v al = {h0.y, h1.y, h2.y, (_Float16)0.f};
                f32x4 acc = {bias1, bias1, bias1, bias1};
                acc = __builtin_amdgcn_mfma_f32_16x16x16f16(ah, bC1, acc, 0, 0, 0);
                acc = __builtin_amdgcn_mfma_f32_16x16x16f16(al, bC1, acc, 0, 0, 0);
                float v = fmaxf(fmaxf(fmaxf(acc.x, acc.y), fmaxf(acc.z, acc.w)), 0.f);
                p1f[wa] = (_Float16)v;
                // p-index += 16 on a 14-wide grid: add-and-select deltas
                X += 2; bool wR = X >= 14; base += wR ? 136 : 84; if (wR) X -= 14;
                c += 2; bool wW = c >= 14; wa   += wW ? 672 : 528; if (wW) c -= 14;
            }
        }
        __syncthreads();   // B1: xhl(e) dead, p1f(e) ready

        // ---- store xhl(e+1) from prefetch regs; issue prefetch x(e+2)
        if (e < 3) {
            #pragma unroll
            for (int it = 0; it < 5; ++it) {
                int j = t + it * 256;
                if (it < 4 || j < 1200) {
                    float v = xr[it];
                    _Float16 h = (_Float16)v;
                    _Float16 lo = (_Float16)(v - (float)h);
                    half2v p; p.x = h; p.y = lo;
                    xhl[j] = __builtin_bit_cast(unsigned, p);
                }
            }
            if (e < 2) {
                const float* xb = xg + (size_t)(b4 + e + 2) * 784;
                #pragma unroll
                for (int it = 0; it < 5; ++it)
                    xr[it] = (xoff[it] >= 0 && b4 + e + 2 < Btot) ? xb[xoff[it]] : 0.f;
            }
        }

        // ---------------- phase 2: conv2 MFMA 16x16x32, pool+relu -> p2s ----
        {
            // B-fragments from LDS; compiler may cache in regs across tiles
            // (good) or re-read per tile (12cy ds_read_b128 - also fine).
            half8v B0[5], B1[5];
            const float4* wf = w2f;
            #pragma unroll
            for (int ks = 0; ks < 5; ++ks) {
                B0[ks] = __builtin_bit_cast(half8v, wf[(ks * 2 + 0) * 64 + lane]);
                B1[ks] = __builtin_bit_cast(half8v, wf[(ks * 2 + 1) * 64 + lane]);
            }
            #pragma unroll
            for (int it2 = 0; it2 < 4; ++it2) {
                if (wv + it2 * 4 < 13) {              // wave-uniform guard
                    f32x4 acc0 = {b20, b20, b20, b20};
                    f32x4 acc1 = {b21, b21, b21, b21};
                    #pragma unroll
                    for (int ks = 0; ks < 5; ++ks) {
                        half8v a = *(const half8v*)(&p1f[a2_[it2] + koff_[ks]]);
                        acc0 = __builtin_amdgcn_mfma_f32_16x16x32_f16(a, B0[ks], acc0, 0, 0, 0);
                        acc1 = __builtin_amdgcn_mfma_f32_16x16x32_f16(a, B1[ks], acc1, 0, 0, 0);
                    }
                    int qO = quadO_[it2];
                    if (qO < 49) {
                        float v0 = fmaxf(fmaxf(fmaxf(acc0.x, acc0.y), fmaxf(acc0.z, acc0.w)), 0.f);
                        float v1 = fmaxf(fmaxf(fmaxf(acc1.x, acc1.y), fmaxf(acc1.z, acc1.w)), 0.f);
                        p2s[lm * 49 + qO] = v0;         // oc = lm
                        p2s[784 + lm * 49 + qO] = v1;   // oc = 16 + lm
                    }
                }
            }
        }
        __syncthreads();   // B2: p2s(e) complete

        // ---------------- dense: p2s x register dw -> angp[e] ---------------
        {
            float dp0 = 0.f, dp1 = 0.f, dp2 = 0.f, dp3 = 0.f;
            #pragma unroll
            for (int k2 = 0; k2 < 7; ++k2) {
                int i = t + k2 * 256;
                if (k2 < 6 || i < 1568) {
                    float v = p2s[i];
                    dp0 = fmaf(v, dwr0[k2], dp0);
                    dp1 = fmaf(v, dwr1[k2], dp1);
                    dp2 = fmaf(v, dwr2[k2], dp2);
                    dp3 = fmaf(v, dwr3[k2], dp3);
                }
            }
            #pragma unroll
            for (int m = 32; m >= 1; m >>= 1) {
                dp0 += __shfl_xor(dp0, m, 64);
                dp1 += __shfl_xor(dp1, m, 64);
                dp2 += __shfl_xor(dp2, m, 64);
                dp3 += __shfl_xor(dp3, m, 64);
            }
            if (lane == 0) {
                float4 dpv = {dp0, dp1, dp2, dp3};
                *(float4*)&angp[e * 16 + wv * 4] = dpv;
            }
        }
        // phase1(e+1) writes p1f (disjoint from p2s); xhl(e+1) pre-B2. Safe.
    }
    __syncthreads();   // angp fully visible

    // ---------------- phase 3: quantum sim + post linear, 1 element/wave ----
    {
        const int bi = b4 + wv;
        const float* ap = angp + wv * 16;
        float4 a0v = *(const float4*)(ap);
        float4 a1v = *(const float4*)(ap + 4);
        float4 a2v = *(const float4*)(ap + 8);
        float4 a3v = *(const float4*)(ap + 12);
        float aw[4] = {a0v.x + a1v.x + a2v.x + a3v.x + dbg[0],
                       a0v.y + a1v.y + a2v.y + a3v.y + dbg[1],
                       a0v.z + a1v.z + a2v.z + a3v.z + dbg[2],
                       a0v.w + a1v.w + a2v.w + a3v.w + dbg[3]};
        int l = lm;
        float re = (l == 0) ? 1.f : 0.f;
        float im = 0.f;
        #pragma unroll
        for (int w = 0; w < 4; ++w) {        // initial RY(angle * pi)
            float th = aw[w] * (PI_F * 0.5f);
            float cth = __cosf(th), sth = __sinf(th);
            gate1(re, im, l, w, C2{cth, 0.f}, C2{-sth, 0.f}, C2{sth, 0.f}, C2{cth, 0.f});
        }
        #pragma unroll
        for (int layer = 0; layer < 2; ++layer) {
            #pragma unroll
            for (int q = 0; q < 4; ++q) {    // precomputed rot gates (uniform)
                const float* gm = grot + (layer * 4 + q) * 8;
                gate1(re, im, l, q, C2{gm[0], gm[1]}, C2{gm[2], gm[3]},
                                     C2{gm[4], gm[5]}, C2{gm[6], gm[7]});
            }
            const int pi_[6] = {0, 0, 0, 1, 1, 2};
            const int pj_[6] = {1, 2, 3, 2, 3, 3};
            #pragma unroll
            for (int k = 0; k < 6; ++k) {    // CNOT(i->j) then RZ on j
                int i = pi_[k], j = pj_[k];
                const float* em = gent + (layer * 6 + k) * 2;
                float ce = em[0], se = em[1];
                int maskj = 1 << (3 - j);
                float pre = __shfl_xor(re, maskj, 64);
                float pim = __shfl_xor(im, maskj, 64);
                bool ci = ((l >> (3 - i)) & 1) != 0;
                re = ci ? pre : re;
                im = ci ? pim : im;
                bool bj = (l & maskj) != 0;
                C2 ph{ce, bj ? se : -se};
                C2 rr = cmul(C2{re, im}, ph);
                re = rr.x; im = rr.y;
            }
        }
        float pr = re * re + im * im;
        float z0 = ((l >> 3) & 1) ? -pr : pr;
        float z1 = ((l >> 2) & 1) ? -pr : pr;
        float z2 = ((l >> 1) & 1) ? -pr : pr;
        float z3 = (l & 1)        ? -pr : pr;
        #pragma unroll
        for (int m = 1; m <= 8; m <<= 1) {
            z0 += __shfl_xor(z0, m, 64);
            z1 += __shfl_xor(z1, m, 64);
            z2 += __shfl_xor(z2, m, 64);
            z3 += __shfl_xor(z3, m, 64);
        }
        if (lane < 10 && bi < Btot) {
            float4 pw4 = *(const float4*)(pwg + lane * 4);
            float o = pbg[lane];
            o = fmaf(z0, pw4.x, o); o = fmaf(z1, pw4.y, o);
            o = fmaf(z2, pw4.z, o); o = fmaf(z3, pw4.w, o);
            out[(size_t)bi * 10 + lane] = o;
        }
    }
}

extern "C" void kernel_launch(void* const* d_in, const int* in_sizes, int n_in,
                              void* d_out, int out_size, void* d_ws, size_t ws_size,
                              hipStream_t stream) {
    const float* x  = (const float*)d_in[0];
    const float* w1 = (const float*)d_in[1];
    const float* b1 = (const float*)d_in[2];
    const float* w2 = (const float*)d_in[3];
    const float* b2 = (const float*)d_in[4];
    const float* dw = (const float*)d_in[5];
    const float* db = (const float*)d_in[6];
    const float* qp = (const float*)d_in[7];
    const float* pw = (const float*)d_in[8];
    const float* pb = (const float*)d_in[9];
    float* out = (float*)d_out;
    int B = in_sizes[0] / 784;   // 4096
    int nb = (B + 3) >> 2;       // 4 elements per block

    qnn_one<<<nb, 256, 0, stream>>>(x, w1, b1, w2, b2, dw, db, qp, pw, pb, out, B);
}